// Round 1
// baseline (264.642 us; speedup 1.0000x reference)
//
#include <hip/hip_runtime.h>
#include <hip/hip_bf16.h>

// DropLearner: per-edge gumbel-sigmoid gate + top-80% selection + symmetric
// degree normalization.
//
// Pipeline (all on `stream`):
//   0. hipMemsetAsync: zero rowsum + histograms + state
//   1. detect_kernel: int32 vs int64 edge_index (JAX may demote int64->int32)
//   2. gate_hist_kernel: gate[e] -> d_out[e], fused level-0 histogram (top 11 bits)
//   3. scan(0) -> hist(1) -> scan(1) -> hist(2) -> scan(2): exact radix select
//      of the k-th largest gate bit pattern (positive floats sort by bits)
//   4. rowsum_kernel: atomicAdd gate into rowsum[row] for kept edges
//   5. dinv_kernel: d = rowsum>0 ? min(rowsum^-0.5, 10) : 10
//   6. values_kernel: d_out[e] = kept ? gate*dinv[row]*dinv[col] : 0 (in-place)

#define BIASF 0.0001f
#define H_DIM 128

__device__ __forceinline__ int load_idx(const void* ei, long long pos, int is64) {
    if (is64) return (int)((const long long*)ei)[pos];
    return ((const int*)ei)[pos];
}

// ---------------------------------------------------------------- detect
__global__ void detect_kernel(const unsigned* __restrict__ ei32,
                              unsigned* __restrict__ state) {
    if (threadIdx.x == 0 && blockIdx.x == 0) {
        unsigned orall = 0;
        // int64 indices < 2^31: every odd 32-bit word is 0.
        // int32 indices: 64 consecutive zeros at odd positions ~ impossible.
        for (int i = 0; i < 64; ++i) orall |= ei32[2 * i + 1];
        state[3] = (orall == 0u) ? 1u : 0u;
    }
}

// ------------------------------------------------------- gate + histogram
// half-wave (32 lanes) per edge; lane loads float4 -> 512B coalesced per row.
__global__ __launch_bounds__(256) void gate_hist_kernel(
    const float* __restrict__ x, const void* __restrict__ ei,
    const float* __restrict__ noise, float* __restrict__ gate_out,
    unsigned* __restrict__ hist0, const unsigned* __restrict__ state,
    long long E, long long EG) {
    __shared__ unsigned lhist[2048];
    for (int i = threadIdx.x; i < 2048; i += 256) lhist[i] = 0;
    __syncthreads();
    const int is64 = (int)state[3];
    const int hw   = threadIdx.x >> 5;   // 0..7  (half-wave id in block)
    const int lane = threadIdx.x & 31;

    for (long long g = blockIdx.x; g < EG; g += gridDim.x) {
        long long e = g * 8 + hw;
        if (e >= E) break;
        int r = load_idx(ei, e, is64);
        int c = load_idx(ei, E + e, is64);
        const float4* xa = (const float4*)(x + (long long)r * H_DIM);
        const float4* xb = (const float4*)(x + (long long)c * H_DIM);
        float4 a = xa[lane];
        float4 b = xb[lane];
        float p = a.x * b.x + a.y * b.y + a.z * b.z + a.w * b.w;
        p += __shfl_xor(p, 16);
        p += __shfl_xor(p, 8);
        p += __shfl_xor(p, 4);
        p += __shfl_xor(p, 2);
        p += __shfl_xor(p, 1);
        if (lane == 0) {
            float nz  = noise[e];
            float eps = (BIASF - (1.0f - BIASF)) * nz + (1.0f - BIASF);
            float ln  = logf(eps) - logf(1.0f - eps);
            float s   = (ln + p) * 2.0f;   // / TEMP_DE (=0.5)
            float gate;
            if (s >= 0.0f) {
                gate = 1.0f / (1.0f + expf(-s));
            } else {
                float ez = expf(s);
                gate = ez / (1.0f + ez);
            }
            gate_out[e] = gate;
            atomicAdd(&lhist[__float_as_uint(gate) >> 21], 1u);
        }
    }
    __syncthreads();
    for (int i = threadIdx.x; i < 2048; i += 256) {
        unsigned v = lhist[i];
        if (v) atomicAdd(&hist0[i], v);
    }
}

// ------------------------------------------------------- refine histograms
__global__ __launch_bounds__(256) void hist_pass_kernel(
    const float* __restrict__ gate, unsigned* __restrict__ hist,
    const unsigned* __restrict__ state, long long E, int level) {
    __shared__ unsigned lh[2048];
    const int nb = (level == 1) ? 2048 : 1024;
    for (int i = threadIdx.x; i < nb; i += 256) lh[i] = 0;
    __syncthreads();
    const unsigned pfx = state[0];
    for (long long e = (long long)blockIdx.x * 256 + threadIdx.x; e < E;
         e += (long long)gridDim.x * 256) {
        unsigned key = __float_as_uint(gate[e]);
        if (level == 1) {
            if ((key >> 21) == (pfx >> 21)) atomicAdd(&lh[(key >> 10) & 2047], 1u);
        } else {
            if ((key >> 10) == (pfx >> 10)) atomicAdd(&lh[key & 1023], 1u);
        }
    }
    __syncthreads();
    for (int i = threadIdx.x; i < nb; i += 256) {
        unsigned v = lh[i];
        if (v) atomicAdd(&hist[i], v);
    }
}

// ------------------------------------------------------------- bin select
// single block; finds bin b with count(> b-range) < kRem <= count(>= b-range)
__global__ __launch_bounds__(256) void scan_kernel(
    const unsigned* __restrict__ hist, unsigned* __restrict__ state,
    int pass, unsigned k0) {
    const int nb    = (pass == 2) ? 1024 : 2048;
    const int shift = (pass == 0) ? 21 : (pass == 1) ? 10 : 0;
    const int C     = nb / 256;
    __shared__ unsigned csum[256];
    __shared__ unsigned sfx[256];
    const unsigned kRem = (pass == 0) ? k0 : state[1];
    const unsigned pfx  = (pass == 0) ? 0u : state[0];
    const int t = threadIdx.x;

    unsigned s = 0;
    for (int i = 0; i < C; ++i) s += hist[t * C + i];
    csum[t] = s;
    __syncthreads();
    if (t == 0) {
        unsigned acc = 0;
        for (int i = 255; i >= 0; --i) { sfx[i] = acc; acc += csum[i]; }
    }
    __syncthreads();
    unsigned g = sfx[t];                 // count of keys strictly above chunk
    for (int j = C - 1; j >= 0; --j) {
        int b = t * C + j;
        unsigned cb = hist[b];
        if (g < kRem && g + cb >= kRem) {
            state[0] = pfx | ((unsigned)b << shift);
            state[1] = kRem - g;
        }
        g += cb;
    }
}

// ---------------------------------------------------------------- rowsum
__global__ __launch_bounds__(256) void rowsum_kernel(
    const float* __restrict__ gate, const void* __restrict__ ei,
    const unsigned* __restrict__ state, float* __restrict__ rowsum,
    long long E) {
    const unsigned tbits = state[0];
    const int is64 = (int)state[3];
    for (long long e = (long long)blockIdx.x * 256 + threadIdx.x; e < E;
         e += (long long)gridDim.x * 256) {
        float gv = gate[e];
        if (__float_as_uint(gv) >= tbits) {
            int r = load_idx(ei, e, is64);
            atomicAdd(&rowsum[r], gv);
        }
    }
}

// ------------------------------------------------------------------ dinv
__global__ __launch_bounds__(256) void dinv_kernel(
    const float* __restrict__ rowsum, float* __restrict__ dinv, int N) {
    int n = blockIdx.x * 256 + threadIdx.x;
    if (n < N) {
        float rs = rowsum[n];
        float d  = 10.0f;
        if (rs > 0.0f) d = fminf(1.0f / sqrtf(rs), 10.0f);
        dinv[n] = d;
    }
}

// ---------------------------------------------------------------- values
__global__ __launch_bounds__(256) void values_kernel(
    float* __restrict__ gate_io, const void* __restrict__ ei,
    const unsigned* __restrict__ state, const float* __restrict__ dinv,
    long long E) {
    const unsigned tbits = state[0];
    const int is64 = (int)state[3];
    for (long long e = (long long)blockIdx.x * 256 + threadIdx.x; e < E;
         e += (long long)gridDim.x * 256) {
        float gv = gate_io[e];
        float v  = 0.0f;
        if (__float_as_uint(gv) >= tbits) {
            int r = load_idx(ei, e, is64);
            int c = load_idx(ei, E + e, is64);
            v = gv * dinv[r] * dinv[c];
        }
        gate_io[e] = v;
    }
}

extern "C" void kernel_launch(void* const* d_in, const int* in_sizes, int n_in,
                              void* d_out, int out_size, void* d_ws, size_t ws_size,
                              hipStream_t stream) {
    const float* x     = (const float*)d_in[0];
    const void*  ei    = d_in[1];
    const float* noise = (const float*)d_in[2];
    float* out = (float*)d_out;

    const long long N = (long long)in_sizes[0] / H_DIM;
    const long long E = (long long)in_sizes[1] / 2;
    const unsigned  k = (unsigned)((double)E * 0.8);  // KEEP_FRAC

    // workspace layout (floats/uints, 4B each)
    float*    rowsum = (float*)d_ws;                  // N
    unsigned* hist0  = (unsigned*)(rowsum + N);       // 2048
    unsigned* hist1  = hist0 + 2048;                  // 2048
    unsigned* hist2  = hist1 + 2048;                  // 1024
    unsigned* state  = hist2 + 1024;                  // 4: {key, kRem, -, is64}
    float*    dinv   = (float*)(state + 4);           // N
    (void)ws_size; (void)n_in; (void)out_size;

    size_t zbytes = (size_t)(N + 2048 + 2048 + 1024 + 4) * 4;
    hipMemsetAsync(d_ws, 0, zbytes, stream);

    detect_kernel<<<1, 64, 0, stream>>>((const unsigned*)ei, state);

    const long long EG = (E + 7) / 8;
    int gblocks = (int)((EG < 2048) ? EG : 2048);
    gate_hist_kernel<<<gblocks, 256, 0, stream>>>(x, ei, noise, out, hist0,
                                                  state, E, EG);

    int eblocks = (int)(((E + 255) / 256 < 2048) ? (E + 255) / 256 : 2048);
    scan_kernel<<<1, 256, 0, stream>>>(hist0, state, 0, k);
    hist_pass_kernel<<<eblocks, 256, 0, stream>>>(out, hist1, state, E, 1);
    scan_kernel<<<1, 256, 0, stream>>>(hist1, state, 1, k);
    hist_pass_kernel<<<eblocks, 256, 0, stream>>>(out, hist2, state, E, 2);
    scan_kernel<<<1, 256, 0, stream>>>(hist2, state, 2, k);

    rowsum_kernel<<<eblocks, 256, 0, stream>>>(out, ei, state, rowsum, E);

    int nblocks = (int)((N + 255) / 256);
    dinv_kernel<<<nblocks, 256, 0, stream>>>(rowsum, dinv, (int)N);

    values_kernel<<<eblocks, 256, 0, stream>>>(out, ei, state, dinv, E);
}